// Round 12
// baseline (2066.648 us; speedup 1.0000x reference)
//
#include <hip/hip_runtime.h>

#define NPTS 256
#define NBATCH 64
#define BIGF 1e30f
#define KBIG 0x7149F200u   // __float_as_uint(1e30f) & 0xFFFFFF00

__device__ __forceinline__ float rlane(float v, int l) {
    return __uint_as_float((unsigned int)__builtin_amdgcn_readlane((int)__float_as_uint(v), l));
}
__device__ __forceinline__ int rlanei(int v, int l) {
    return __builtin_amdgcn_readlane(v, l);
}
__device__ __forceinline__ float rawsqrt(float x) {
    return __builtin_amdgcn_sqrtf(x);
}

// Uniform-slot select (slot wave-uniform); cold paths only.
#define SEL4(a, s) ((s) == 0 ? a[0] : (s) == 1 ? a[1] : (s) == 2 ? a[2] : a[3])

#define DPP_UMIN(v, ctrl) \
    (min)((v), (unsigned int)__builtin_amdgcn_update_dpp( \
        (int)(v), (int)(v), (ctrl), 0xf, 0xf, false))

__global__ void zero_out_kernel(float* out, int n) {
    int i = blockIdx.x * blockDim.x + threadIdx.x;
    if (i < n) out[i] = 0.0f;
}

// One wave per batch; lane owns columns/rows {lane, 64+lane, 128+lane, 192+lane}.
// JV with TWO-PHASE reduction (R12): row reduction u0[i]=min_j d, then column
// reduction on reduced costs v[j]=min_i(d-u0) -> tighter duals -> smaller
// Dijkstra trees. Hot loop = R10's proven body (switch fetch, exec-mask
// bookkeeping, sentinel exclusion, split DPP/SALU reduce) + fmaxf(cand,0)
// guard (two-phase zero-slack edges can round negative; sign bit would rank
// them last in unsigned key order).
__launch_bounds__(64, 1)
__global__ void hungarian_wave(const float* __restrict__ pred,
                               const float* __restrict__ target,
                               float* __restrict__ out) {
    const int b    = blockIdx.x;
    const int lane = threadIdx.x;

    const float* pb = pred   + (size_t)b * NPTS * 3;
    const float* tb = target + (size_t)b * NPTS * 3;

    float prx[4], pry[4], prz[4];      // pred (row) points, row = c*64+lane
    float tx[4], ty[4], tz[4];         // target (col) points, col = c*64+lane
    float u0[4];                       // initial row duals, row-distributed
    float vv[4], upc[4], Tv[4], w[4], vsave[4];
    float rxc[4], ryc[4], rzc[4];      // matched-row coords, column-attached
    unsigned int kMv[4];               // packed slack keys: (bits(M)&~0xFF)|col
    int   pc[4]  = {-1, -1, -1, -1};   // matched row per column (-1 = free)
    int   way[4];
    unsigned int colu[4];              // this lane's column ids
    unsigned long long freem[4];       // free-COLUMN masks (wave-uniform)

#pragma unroll
    for (int c = 0; c < 4; ++c) {
        int idx = c * 64 + lane;
        prx[c] = pb[idx * 3 + 0]; pry[c] = pb[idx * 3 + 1]; prz[c] = pb[idx * 3 + 2];
        tx[c]  = tb[idx * 3 + 0]; ty[c]  = tb[idx * 3 + 1]; tz[c]  = tb[idx * 3 + 2];
        upc[c] = 0.f; Tv[c] = 0.f; vsave[c] = 0.f;
        rxc[c] = 0.f; ryc[c] = 0.f; rzc[c] = 0.f;
        colu[c] = (unsigned int)idx;
        freem[c] = ~0ull;
        u0[c] = BIGF;
    }

    // ---- Phase 0: row reduction. u0[r] = min_j d(row r, col j) ----
#pragma unroll
    for (int cs = 0; cs < 4; ++cs) {
        for (int l = 0; l < 64; ++l) {
            float cx = rlane(tx[cs], l), cy = rlane(ty[cs], l), cz = rlane(tz[cs], l);
#pragma unroll
            for (int r = 0; r < 4; ++r) {
                float dx = prx[r] - cx, dy = pry[r] - cy, dz = prz[r] - cz;
                float d = rawsqrt(dx * dx + dy * dy + dz * dz);
                u0[r] = fminf(u0[r], d);
            }
        }
    }

    // ---- Phase 1a: column reduction on REDUCED costs.
    //      vv[c] = min_r (d(r,col) - u0[r]), colrow = argmin ----
    float colmin[4] = {BIGF, BIGF, BIGF, BIGF};
    int   colrow[4] = {0, 0, 0, 0};
#pragma unroll
    for (int rs = 0; rs < 4; ++rs) {
        for (int rl = 0; rl < 64; ++rl) {
            float bx = rlane(prx[rs], rl), by = rlane(pry[rs], rl), bz = rlane(prz[rs], rl);
            float bu = rlane(u0[rs], rl);
            int r = rs * 64 + rl;
#pragma unroll
            for (int c = 0; c < 4; ++c) {
                float dx = bx - tx[c], dy = by - ty[c], dz = bz - tz[c];
                float d = rawsqrt(dx * dx + dy * dy + dz * dz) - bu;
                if (d < colmin[c]) { colmin[c] = d; colrow[c] = r; }
            }
        }
    }
#pragma unroll
    for (int c = 0; c < 4; ++c) vv[c] = colmin[c];

    // ---- Phase 1b: greedy claim — column (ascending) claims its argmin row if free.
    //      Claimed pair has zero reduced cost (CS); column attaches u0[row]. ----
    unsigned long long frm[4];         // free-row masks (wave-uniform values)
    frm[0] = frm[1] = frm[2] = frm[3] = ~0ull;
#pragma unroll
    for (int cs = 0; cs < 4; ++cs) {
        for (int l = 0; l < 64; ++l) {
            int r = rlanei(colrow[cs], l);
            int rs = r >> 6, rl2 = r & 63;
            unsigned long long bit = 1ull << rl2;
            bool free_row = (SEL4(frm, rs) & bit) != 0ull;
            if (free_row) {
#pragma unroll
                for (int s = 0; s < 4; ++s)
                    if (s == rs) frm[s] &= ~bit;
                float bx, by, bz, bu;
                switch (rs) {
                    case 0:  bx = rlane(prx[0], rl2); by = rlane(pry[0], rl2); bz = rlane(prz[0], rl2); bu = rlane(u0[0], rl2); break;
                    case 1:  bx = rlane(prx[1], rl2); by = rlane(pry[1], rl2); bz = rlane(prz[1], rl2); bu = rlane(u0[1], rl2); break;
                    case 2:  bx = rlane(prx[2], rl2); by = rlane(pry[2], rl2); bz = rlane(prz[2], rl2); bu = rlane(u0[2], rl2); break;
                    default: bx = rlane(prx[3], rl2); by = rlane(pry[3], rl2); bz = rlane(prz[3], rl2); bu = rlane(u0[3], rl2); break;
                }
                if (lane == l) {
                    pc[cs] = r; upc[cs] = bu;
                    rxc[cs] = bx; ryc[cs] = by; rzc[cs] = bz;
                }
#pragma unroll
                for (int s = 0; s < 4; ++s)
                    if (s == cs) freem[s] &= ~(1ull << l);   // column cs*64+l matched
            }
        }
    }

    // ---- Phase 2: Dijkstra shortest-path for remaining free rows ----
#pragma unroll
    for (int is = 0; is < 4; ++is) {
        unsigned long long m = frm[is];
        while (m) {
            const int il = (int)__builtin_ctzll(m);
            m &= (m - 1);
            const int i = is * 64 + il;

            float rootx, rooty, rootz, u0r;
            switch (is) {
                case 0:  rootx = rlane(prx[0], il); rooty = rlane(pry[0], il); rootz = rlane(prz[0], il); u0r = rlane(u0[0], il); break;
                case 1:  rootx = rlane(prx[1], il); rooty = rlane(pry[1], il); rootz = rlane(prz[1], il); u0r = rlane(u0[1], il); break;
                case 2:  rootx = rlane(prx[2], il); rooty = rlane(pry[2], il); rootz = rlane(prz[2], il); u0r = rlane(u0[2], il); break;
                default: rootx = rlane(prx[3], il); rooty = rlane(pry[3], il); rootz = rlane(prz[3], il); u0r = rlane(u0[3], il); break;
            }

#pragma unroll
            for (int c = 0; c < 4; ++c) {
                kMv[c] = KBIG | colu[c];
                w[c]   = -u0r - vv[c];     // root ukey = u0[root], D_entry = 0
            }
            int usedm = 0;

            float bx = rootx, by = rooty, bz = rootz;
            int j0 = -1;
            int jfin = 0;
            float D = 0.f;

            while (true) {
                // Relax all columns; used columns excluded by sentinel
                // (w = gu + BIGF -> cand = BIGF -> kc == kMv -> frozen).
#pragma unroll
                for (int c = 0; c < 4; ++c) {
                    float dx = bx - tx[c], dy = by - ty[c], dz = bz - tz[c];
                    float d = rawsqrt(dx * dx + dy * dy + dz * dz);
                    float cand = fmaxf(d + w[c], 0.f);  // == d - ukey - vv[c], clamped
                    unsigned int kc = (__float_as_uint(cand) & 0xFFFFFF00u) | colu[c];
                    if (kc < kMv[c]) { kMv[c] = kc; way[c] = j0; }
                }
                unsigned int v = (min)((min)(kMv[0], kMv[1]), (min)(kMv[2], kMv[3]));
                // 4 DPP row-steps -> row minima in lanes 15/31/47/63
                v = DPP_UMIN(v, 0x111);   // row_shr:1
                v = DPP_UMIN(v, 0x112);   // row_shr:2
                v = DPP_UMIN(v, 0x114);   // row_shr:4
                v = DPP_UMIN(v, 0x118);   // row_shr:8
                const unsigned int r0 = (unsigned int)rlanei((int)v, 15);
                const unsigned int r1 = (unsigned int)rlanei((int)v, 31);
                const unsigned int r2 = (unsigned int)rlanei((int)v, 47);
                const unsigned int r3 = (unsigned int)rlanei((int)v, 63);
                const unsigned int kk = (min)((min)(r0, r1), (min)(r2, r3));

                const int   j1   = (int)(kk & 0xFFu);
                const float gmin = __uint_as_float(kk & 0xFFFFFF00u);
                const int osl = j1 >> 6, oln = j1 & 63;

                // Speculative state readlanes (issued before the exit branch)
                float uj, nbx, nby, nbz;
                switch (osl) {
                    case 0:  uj = rlane(upc[0], oln); nbx = rlane(rxc[0], oln); nby = rlane(ryc[0], oln); nbz = rlane(rzc[0], oln); break;
                    case 1:  uj = rlane(upc[1], oln); nbx = rlane(rxc[1], oln); nby = rlane(ryc[1], oln); nbz = rlane(rzc[1], oln); break;
                    case 2:  uj = rlane(upc[2], oln); nbx = rlane(rxc[2], oln); nby = rlane(ryc[2], oln); nbz = rlane(rzc[2], oln); break;
                    default: uj = rlane(upc[3], oln); nbx = rlane(rxc[3], oln); nby = rlane(ryc[3], oln); nbz = rlane(rzc[3], oln); break;
                }

                // SALU free-column test (wave-uniform masks, no readlane)
                const unsigned long long fm =
                    (osl == 0 ? freem[0] : osl == 1 ? freem[1] : osl == 2 ? freem[2] : freem[3]);
                if ((fm >> oln) & 1ull) { jfin = j1; D = gmin; break; }

                // Owner bookkeeping (off critical path): mark used via sentinels
#pragma unroll
                for (int c = 0; c < 4; ++c)
                    if (c == osl && lane == oln) {
                        usedm |= (1 << c);
                        Tv[c] = gmin;
                        vsave[c] = vv[c];
                        vv[c] = -BIGF;                 // -> w = +BIGF -> excluded
                        kMv[c] = KBIG | colu[c];       // frozen
                    }

                // Next-iteration adjust, off the dist critical path
                const float gu = gmin - uj;
#pragma unroll
                for (int c = 0; c < 4; ++c) w[c] = gu - vv[c];

                bx = nbx; by = nby; bz = nbz;
                j0 = j1;
            }

            // Commit duals for tree columns: net amount = D_final - D_at_use
#pragma unroll
            for (int c = 0; c < 4; ++c)
                if ((usedm >> c) & 1) {
                    vv[c] = vsave[c] + Tv[c] - D;
                    upc[c] += D - Tv[c];
                }

            // Newly matched column leaves the free set
            {
                const int wsl = jfin >> 6;
                const unsigned long long bit = 1ull << (jfin & 63);
#pragma unroll
                for (int s = 0; s < 4; ++s)
                    if (s == wsl) freem[s] &= ~bit;
            }

            // Augment along alternating path (cold)
            int jc = jfin;
            while (true) {
                const int osl = jc >> 6, oln = jc & 63;
                int jw;
                switch (osl) {
                    case 0:  jw = rlanei(way[0], oln); break;
                    case 1:  jw = rlanei(way[1], oln); break;
                    case 2:  jw = rlanei(way[2], oln); break;
                    default: jw = rlanei(way[3], oln); break;
                }
                int np_; float nup, nrx, nry, nrz;
                if (jw < 0) {   // root enters with u = u0[root] + D
                    np_ = i; nup = u0r + D; nrx = rootx; nry = rooty; nrz = rootz;
                } else {
                    const int wsl = jw >> 6, wln = jw & 63;
                    switch (wsl) {
                        case 0:  np_ = rlanei(pc[0], wln); nup = rlane(upc[0], wln); nrx = rlane(rxc[0], wln); nry = rlane(ryc[0], wln); nrz = rlane(rzc[0], wln); break;
                        case 1:  np_ = rlanei(pc[1], wln); nup = rlane(upc[1], wln); nrx = rlane(rxc[1], wln); nry = rlane(ryc[1], wln); nrz = rlane(rzc[1], wln); break;
                        case 2:  np_ = rlanei(pc[2], wln); nup = rlane(upc[2], wln); nrx = rlane(rxc[2], wln); nry = rlane(ryc[2], wln); nrz = rlane(rzc[2], wln); break;
                        default: np_ = rlanei(pc[3], wln); nup = rlane(upc[3], wln); nrx = rlane(rxc[3], wln); nry = rlane(ryc[3], wln); nrz = rlane(rzc[3], wln); break;
                    }
                }
#pragma unroll
                for (int c = 0; c < 4; ++c)
                    if (c == osl && lane == oln) {
                        pc[c] = np_; upc[c] = nup;
                        rxc[c] = nrx; ryc[c] = nry; rzc[c] = nrz;
                    }
                if (jw < 0) break;
                jc = jw;
            }
        }
    }

    // ---- Matched cost (coords column-attached; IEEE sqrt for final accuracy) ----
    float s = 0.f;
#pragma unroll
    for (int c = 0; c < 4; ++c) {
        float dx = rxc[c] - tx[c], dy = ryc[c] - ty[c], dz = rzc[c] - tz[c];
        s += sqrtf(dx * dx + dy * dy + dz * dz);
    }
#pragma unroll
    for (int off = 1; off < 64; off <<= 1) s += __shfl_xor(s, off, 64);
    if (lane == 0) atomicAdd(out, s / (float)NBATCH);
}

extern "C" void kernel_launch(void* const* d_in, const int* in_sizes, int n_in,
                              void* d_out, int out_size, void* d_ws, size_t ws_size,
                              hipStream_t stream) {
    const float* pred   = (const float*)d_in[0];
    const float* target = (const float*)d_in[1];
    float* out = (float*)d_out;

    zero_out_kernel<<<1, 64, 0, stream>>>(out, out_size);
    hungarian_wave<<<NBATCH, 64, 0, stream>>>(pred, target, out);
}

// Round 13
// 1830.423 us; speedup vs baseline: 1.1291x; 1.1291x over previous
//
#include <hip/hip_runtime.h>

#define NPTS 256
#define NBATCH 64
#define BIGF 1e30f
#define KBIG 0x7149F200u   // __float_as_uint(1e30f) & 0xFFFFFF00

__device__ __forceinline__ float rlane(float v, int l) {
    return __uint_as_float((unsigned int)__builtin_amdgcn_readlane((int)__float_as_uint(v), l));
}
__device__ __forceinline__ int rlanei(int v, int l) {
    return __builtin_amdgcn_readlane(v, l);
}
__device__ __forceinline__ float rawsqrt(float x) {
    return __builtin_amdgcn_sqrtf(x);
}

// Uniform-slot select (slot wave-uniform); cold paths only.
#define SEL4(a, s) ((s) == 0 ? a[0] : (s) == 1 ? a[1] : (s) == 2 ? a[2] : a[3])

#define DPP_UMIN(v, ctrl) \
    (min)((v), (unsigned int)__builtin_amdgcn_update_dpp( \
        (int)(v), (int)(v), (ctrl), 0xf, 0xf, false))

__global__ void zero_out_kernel(float* out, int n) {
    int i = blockIdx.x * blockDim.x + threadIdx.x;
    if (i < n) out[i] = 0.0f;
}

// One expansion step of the delta-accumulated Dijkstra (R10 dataflow).
// Reduce = 3 DPP row_shr (8-block minima in lanes 7,15,..,63) + 8 parallel
// readlanes + SALU min tree. `break` exits the enclosing while on augment.
#define EXPAND_ONCE                                                              \
    {                                                                            \
        _Pragma("unroll")                                                        \
        for (int c = 0; c < 4; ++c) {                                            \
            float dx = bx - tx[c], dy = by - ty[c], dz = bz - tz[c];             \
            float d = rawsqrt(dx * dx + dy * dy + dz * dz);                      \
            float cand = d + w[c];              /* == d - ukey - vv[c] */        \
            unsigned int kc = (__float_as_uint(cand) & 0xFFFFFF00u) | colu[c];   \
            if (kc < kMv[c]) { kMv[c] = kc; way[c] = j0; }                       \
        }                                                                        \
        unsigned int vr = (min)((min)(kMv[0], kMv[1]), (min)(kMv[2], kMv[3]));   \
        vr = DPP_UMIN(vr, 0x111);   /* row_shr:1 */                              \
        vr = DPP_UMIN(vr, 0x112);   /* row_shr:2 */                              \
        vr = DPP_UMIN(vr, 0x114);   /* row_shr:4 */                              \
        const unsigned int q0 = (unsigned int)rlanei((int)vr, 7);                \
        const unsigned int q1 = (unsigned int)rlanei((int)vr, 15);               \
        const unsigned int q2 = (unsigned int)rlanei((int)vr, 23);               \
        const unsigned int q3 = (unsigned int)rlanei((int)vr, 31);               \
        const unsigned int q4 = (unsigned int)rlanei((int)vr, 39);               \
        const unsigned int q5 = (unsigned int)rlanei((int)vr, 47);               \
        const unsigned int q6 = (unsigned int)rlanei((int)vr, 55);               \
        const unsigned int q7 = (unsigned int)rlanei((int)vr, 63);               \
        const unsigned int kk = (min)((min)((min)(q0, q1), (min)(q2, q3)),       \
                                      (min)((min)(q4, q5), (min)(q6, q7)));      \
        const int   j1   = (int)(kk & 0xFFu);                                    \
        const float gmin = __uint_as_float(kk & 0xFFFFFF00u);                    \
        const int osl = j1 >> 6, oln = j1 & 63;                                  \
        float uj, nbx, nby, nbz;                                                 \
        switch (osl) {                                                           \
            case 0:  uj = rlane(upc[0], oln); nbx = rlane(rxc[0], oln); nby = rlane(ryc[0], oln); nbz = rlane(rzc[0], oln); break; \
            case 1:  uj = rlane(upc[1], oln); nbx = rlane(rxc[1], oln); nby = rlane(ryc[1], oln); nbz = rlane(rzc[1], oln); break; \
            case 2:  uj = rlane(upc[2], oln); nbx = rlane(rxc[2], oln); nby = rlane(ryc[2], oln); nbz = rlane(rzc[2], oln); break; \
            default: uj = rlane(upc[3], oln); nbx = rlane(rxc[3], oln); nby = rlane(ryc[3], oln); nbz = rlane(rzc[3], oln); break; \
        }                                                                        \
        const unsigned long long fm =                                            \
            (osl == 0 ? freem[0] : osl == 1 ? freem[1] : osl == 2 ? freem[2] : freem[3]); \
        if ((fm >> oln) & 1ull) { jfin = j1; D = gmin; break; }                  \
        _Pragma("unroll")                                                        \
        for (int c = 0; c < 4; ++c)                                              \
            if (c == osl && lane == oln) {                                       \
                usedm |= (1 << c);                                               \
                Tv[c] = gmin;                                                    \
                vsave[c] = vv[c];                                                \
                vv[c] = -BIGF;                 /* -> w = +BIGF -> excluded */    \
                kMv[c] = KBIG | colu[c];       /* frozen */                      \
            }                                                                    \
        const float gu = gmin - uj;                                              \
        _Pragma("unroll")                                                        \
        for (int c = 0; c < 4; ++c) w[c] = gu - vv[c];                           \
        bx = nbx; by = nby; bz = nbz;                                            \
        j0 = j1;                                                                 \
    }

// One wave per batch; lane owns columns/rows {lane, 64+lane, 128+lane, 192+lane}.
// JV: column reduction -> greedy claim -> delta-accumulated Dijkstra searches.
// R13 = R10 (best known: sentinel exclusion, switch fetch, SALU free-test)
// + expansion loop unrolled x2 (backedge amortized; iter-k tail overlaps
// iter-k+1 relax) + 3-DPP/8-readlane shallow reduce. Column-min v with u=0 is
// the empirically best dual init (R6/R12 falsified both strengthening orders).
__launch_bounds__(64, 1)
__global__ void hungarian_wave(const float* __restrict__ pred,
                               const float* __restrict__ target,
                               float* __restrict__ out) {
    const int b    = blockIdx.x;
    const int lane = threadIdx.x;

    const float* pb = pred   + (size_t)b * NPTS * 3;
    const float* tb = target + (size_t)b * NPTS * 3;

    float prx[4], pry[4], prz[4];      // pred (row) points, row = c*64+lane
    float tx[4], ty[4], tz[4];         // target (col) points, col = c*64+lane
    float vv[4], upc[4], Tv[4], w[4], vsave[4];
    float rxc[4], ryc[4], rzc[4];      // matched-row coords, column-attached
    unsigned int kMv[4];               // packed slack keys: (bits(M)&~0xFF)|col
    int   pc[4]  = {-1, -1, -1, -1};   // matched row per column (-1 = free)
    int   way[4];
    unsigned int colu[4];              // this lane's column ids
    unsigned long long freem[4];       // free-COLUMN masks (wave-uniform)

#pragma unroll
    for (int c = 0; c < 4; ++c) {
        int idx = c * 64 + lane;
        prx[c] = pb[idx * 3 + 0]; pry[c] = pb[idx * 3 + 1]; prz[c] = pb[idx * 3 + 2];
        tx[c]  = tb[idx * 3 + 0]; ty[c]  = tb[idx * 3 + 1]; tz[c]  = tb[idx * 3 + 2];
        upc[c] = 0.f; Tv[c] = 0.f; vsave[c] = 0.f;
        rxc[c] = 0.f; ryc[c] = 0.f; rzc[c] = 0.f;
        colu[c] = (unsigned int)idx;
        freem[c] = ~0ull;
    }

    // ---- Phase 1a: column reduction. vv[c] = min_r d(r, col), colrow = argmin ----
    float colmin[4] = {BIGF, BIGF, BIGF, BIGF};
    int   colrow[4] = {0, 0, 0, 0};
#pragma unroll
    for (int rs = 0; rs < 4; ++rs) {
        for (int rl = 0; rl < 64; ++rl) {
            float bx = rlane(prx[rs], rl), by = rlane(pry[rs], rl), bz = rlane(prz[rs], rl);
            int r = rs * 64 + rl;
#pragma unroll
            for (int c = 0; c < 4; ++c) {
                float dx = bx - tx[c], dy = by - ty[c], dz = bz - tz[c];
                float d = rawsqrt(dx * dx + dy * dy + dz * dz);
                if (d < colmin[c]) { colmin[c] = d; colrow[c] = r; }
            }
        }
    }
#pragma unroll
    for (int c = 0; c < 4; ++c) vv[c] = colmin[c];

    // ---- Phase 1b: greedy claim — column (ascending) claims its argmin row if free ----
    unsigned long long frm[4];         // free-row masks (wave-uniform values)
    frm[0] = frm[1] = frm[2] = frm[3] = ~0ull;
#pragma unroll
    for (int cs = 0; cs < 4; ++cs) {
        for (int l = 0; l < 64; ++l) {
            int r = rlanei(colrow[cs], l);
            int rs = r >> 6, rl2 = r & 63;
            unsigned long long bit = 1ull << rl2;
            bool free_row = (SEL4(frm, rs) & bit) != 0ull;
            if (free_row) {
#pragma unroll
                for (int s = 0; s < 4; ++s)
                    if (s == rs) frm[s] &= ~bit;
                float bx, by, bz;
                switch (rs) {
                    case 0:  bx = rlane(prx[0], rl2); by = rlane(pry[0], rl2); bz = rlane(prz[0], rl2); break;
                    case 1:  bx = rlane(prx[1], rl2); by = rlane(pry[1], rl2); bz = rlane(prz[1], rl2); break;
                    case 2:  bx = rlane(prx[2], rl2); by = rlane(pry[2], rl2); bz = rlane(prz[2], rl2); break;
                    default: bx = rlane(prx[3], rl2); by = rlane(pry[3], rl2); bz = rlane(prz[3], rl2); break;
                }
                if (lane == l) {
                    pc[cs] = r; upc[cs] = 0.f;
                    rxc[cs] = bx; ryc[cs] = by; rzc[cs] = bz;
                }
#pragma unroll
                for (int s = 0; s < 4; ++s)
                    if (s == cs) freem[s] &= ~(1ull << l);   // column cs*64+l matched
            }
        }
    }

    // ---- Phase 2: Dijkstra shortest-path for remaining free rows ----
#pragma unroll
    for (int is = 0; is < 4; ++is) {
        unsigned long long m = frm[is];
        while (m) {
            const int il = (int)__builtin_ctzll(m);
            m &= (m - 1);
            const int i = is * 64 + il;

            float rootx, rooty, rootz;
            switch (is) {
                case 0:  rootx = rlane(prx[0], il); rooty = rlane(pry[0], il); rootz = rlane(prz[0], il); break;
                case 1:  rootx = rlane(prx[1], il); rooty = rlane(pry[1], il); rootz = rlane(prz[1], il); break;
                case 2:  rootx = rlane(prx[2], il); rooty = rlane(pry[2], il); rootz = rlane(prz[2], il); break;
                default: rootx = rlane(prx[3], il); rooty = rlane(pry[3], il); rootz = rlane(prz[3], il); break;
            }

#pragma unroll
            for (int c = 0; c < 4; ++c) {
                kMv[c] = KBIG | colu[c];
                w[c]   = -vv[c];
            }
            int usedm = 0;

            float bx = rootx, by = rooty, bz = rootz;
            int j0 = -1;
            int jfin = 0;
            float D = 0.f;

            while (true) {
                EXPAND_ONCE
                EXPAND_ONCE
            }

            // Commit duals for tree columns: net amount = D_final - D_at_use
#pragma unroll
            for (int c = 0; c < 4; ++c)
                if ((usedm >> c) & 1) {
                    vv[c] = vsave[c] + Tv[c] - D;
                    upc[c] += D - Tv[c];
                }

            // Newly matched column leaves the free set
            {
                const int wsl = jfin >> 6;
                const unsigned long long bit = 1ull << (jfin & 63);
#pragma unroll
                for (int s = 0; s < 4; ++s)
                    if (s == wsl) freem[s] &= ~bit;
            }

            // Augment along alternating path (cold)
            int jc = jfin;
            while (true) {
                const int osl = jc >> 6, oln = jc & 63;
                int jw;
                switch (osl) {
                    case 0:  jw = rlanei(way[0], oln); break;
                    case 1:  jw = rlanei(way[1], oln); break;
                    case 2:  jw = rlanei(way[2], oln); break;
                    default: jw = rlanei(way[3], oln); break;
                }
                int np_; float nup, nrx, nry, nrz;
                if (jw < 0) {
                    np_ = i; nup = D; nrx = rootx; nry = rooty; nrz = rootz;
                } else {
                    const int wsl = jw >> 6, wln = jw & 63;
                    switch (wsl) {
                        case 0:  np_ = rlanei(pc[0], wln); nup = rlane(upc[0], wln); nrx = rlane(rxc[0], wln); nry = rlane(ryc[0], wln); nrz = rlane(rzc[0], wln); break;
                        case 1:  np_ = rlanei(pc[1], wln); nup = rlane(upc[1], wln); nrx = rlane(rxc[1], wln); nry = rlane(ryc[1], wln); nrz = rlane(rzc[1], wln); break;
                        case 2:  np_ = rlanei(pc[2], wln); nup = rlane(upc[2], wln); nrx = rlane(rxc[2], wln); nry = rlane(ryc[2], wln); nrz = rlane(rzc[2], wln); break;
                        default: np_ = rlanei(pc[3], wln); nup = rlane(upc[3], wln); nrx = rlane(rxc[3], wln); nry = rlane(ryc[3], wln); nrz = rlane(rzc[3], wln); break;
                    }
                }
#pragma unroll
                for (int c = 0; c < 4; ++c)
                    if (c == osl && lane == oln) {
                        pc[c] = np_; upc[c] = nup;
                        rxc[c] = nrx; ryc[c] = nry; rzc[c] = nrz;
                    }
                if (jw < 0) break;
                jc = jw;
            }
        }
    }

    // ---- Matched cost (coords column-attached; IEEE sqrt for final accuracy) ----
    float s = 0.f;
#pragma unroll
    for (int c = 0; c < 4; ++c) {
        float dx = rxc[c] - tx[c], dy = ryc[c] - ty[c], dz = rzc[c] - tz[c];
        s += sqrtf(dx * dx + dy * dy + dz * dz);
    }
#pragma unroll
    for (int off = 1; off < 64; off <<= 1) s += __shfl_xor(s, off, 64);
    if (lane == 0) atomicAdd(out, s / (float)NBATCH);
}

extern "C" void kernel_launch(void* const* d_in, const int* in_sizes, int n_in,
                              void* d_out, int out_size, void* d_ws, size_t ws_size,
                              hipStream_t stream) {
    const float* pred   = (const float*)d_in[0];
    const float* target = (const float*)d_in[1];
    float* out = (float*)d_out;

    zero_out_kernel<<<1, 64, 0, stream>>>(out, out_size);
    hungarian_wave<<<NBATCH, 64, 0, stream>>>(pred, target, out);
}